// Round 12
// baseline (285.037 us; speedup 1.0000x reference)
//
#include <hip/hip_runtime.h>

#define NN 300000
#define NE 600000
#define NG 12000
#define HH 128
#define FA 9
#define VA 119
#define DA 9
#define AGS 5                          // packed bf16 row stride in u32 (20B rows)
#define NCHUNK ((NN + 1023) / 1024)   // 293

// canonical f32 weight scratch offsets
#define OEMB 0
#define OW1  (FA*VA*DA)            // 9639
#define OB1  (OW1 + DA*HH)         // 10791
#define OW2  (OB1 + HH)            // 10919
#define OB2  (OW2 + HH*HH)         // 27303
#define OWFC (OB2 + HH)            // 27431
#define OBFC (OWFC + HH*HH)        // 43815
#define NWC  (OBFC + HH)           // 43943

typedef unsigned short u16;
typedef unsigned int u32;
typedef __attribute__((ext_vector_type(8))) short bfrag8;   // 8 bf16 (4 VGPRs)
typedef __attribute__((ext_vector_type(4))) float ffrag4;   // 4 f32 acc

__device__ __forceinline__ float bf2f(u16 u){
  union { u32 i; float f; } v; v.i = ((u32)u) << 16; return v.f;
}
__device__ __forceinline__ float bflo(u32 w){
  union { u32 i; float f; } v; v.i = w << 16; return v.f;
}
__device__ __forceinline__ float bfhi(u32 w){
  union { u32 i; float f; } v; v.i = w & 0xFFFF0000u; return v.f;
}
__device__ __forceinline__ u16 f2bf(float f){
  union { float f; u32 i; } v; v.f = f;
  u32 x = v.i;
  return (u16)((x + 0x7FFFu + ((x >> 16) & 1u)) >> 16);
}
__device__ __forceinline__ float ldf(const void* p, int i, int isf32){
  return isf32 ? ((const float*)p)[i] : bf2f(((const u16*)p)[i]);
}
// per-block dtype detect (validated round 3)
__device__ __forceinline__ int detect_isf32(const u16* emb16, int t, int* scnt){
  if (t == 0) *scnt = 0;
  __syncthreads();
  u16 u = emb16[t];
  int e = (u >> 7) & 0xFF;
  if (e >= 96 && e < 126) atomicAdd(scnt, 1);
  __syncthreads();
  return (*scnt >= 200) ? 0 : 1;
}

// ---- k_pre: detect + deg-histogram (captures rank[e]) + canonicalize wc +
//      gstart + embed->h0u + wcomb/bcomb/btab co-work ----
__global__ void k_pre(const int* __restrict__ x, const void* emb, const void* W1,
                      const void* b1, const void* W2, const void* b2,
                      const void* Wfc, const void* bfc,
                      const int* __restrict__ batch, const int* __restrict__ dst,
                      int* __restrict__ flag, float* __restrict__ wc,
                      int* __restrict__ degcur, u16* __restrict__ rank,
                      int* __restrict__ gstart, u32* __restrict__ h0u,
                      float* __restrict__ wcomb, float* __restrict__ bcomb,
                      u32* __restrict__ btab){
  __shared__ float embS[FA * VA * DA];   // 38.6 KB
  __shared__ int scnt;
  int t = threadIdx.x;
  int isf32 = detect_isf32((const u16*)emb, t, &scnt);
  int tid = blockIdx.x * 256 + t;
  int nth = gridDim.x * 256;
  if (tid == 0) flag[0] = isf32;

  // degree histogram: 2 edges/thread; return value = rank within dst
  {
    int e0 = tid * 2;
    if (e0 < NE){
      int r0 = atomicAdd(&degcur[dst[e0]], 1);
      rank[e0] = (u16)r0;
    }
    if (e0 + 1 < NE){
      int r1 = atomicAdd(&degcur[dst[e0 + 1]], 1);
      rank[e0 + 1] = (u16)r1;
    }
  }

  for (int i = t; i < FA * VA * DA; i += 256) embS[i] = ldf(emb, i, isf32);
  for (int i = tid; i < NWC; i += nth){
    float v;
    if      (i < OW1)  v = ldf(emb, i - OEMB, isf32);
    else if (i < OB1)  v = ldf(W1,  i - OW1,  isf32);
    else if (i < OW2)  v = ldf(b1,  i - OB1,  isf32);
    else if (i < OB2)  v = ldf(W2,  i - OW2,  isf32);
    else if (i < OWFC) v = ldf(b2,  i - OB2,  isf32);
    else if (i < OBFC) v = ldf(Wfc, i - OWFC, isf32);
    else               v = ldf(bfc, i - OBFC, isf32);
    wc[i] = v;
  }

  // head-weight co-work: Wc = W2@Wfc, bc = b2@Wfc, MFMA B-frag table
  if (tid < HH * HH){
    int d = tid >> 7, k = tid & 127;
    float s = 0.f;
    #pragma unroll 4
    for (int j = 0; j < HH; ++j) s += ldf(W2, d * HH + j, isf32) * ldf(Wfc, j * HH + k, isf32);
    wcomb[tid] = s;
    if (tid < HH){
      float sb = 0.f;
      #pragma unroll 4
      for (int j = 0; j < HH; ++j) sb += ldf(b2, j, isf32) * ldf(Wfc, j * HH + tid, isf32);
      bcomb[tid] = sb;
    }
    if (tid < 2048){
      // btab[lane*32 + tile*4 + reg]: B[k=(lane>>4)*8 + 2*reg + {0,1}][n=tile*16+(lane&15)]
      int lane = tid >> 5, idx = tid & 31;
      int tile = idx >> 2, reg = idx & 3;
      int kq = lane >> 4, li = lane & 15;
      int nn = tile * 16 + li;
      int k0 = kq * 8 + reg * 2;
      int k1 = k0 + 1;
      u32 lo = 0, hi = 0;
      if (k0 < 9)       lo = f2bf(ldf(W1, k0 * HH + nn, isf32));
      else if (k0 == 9) lo = f2bf(ldf(b1, nn, isf32));
      if (k1 < 9)       hi = f2bf(ldf(W1, k1 * HH + nn, isf32));
      else if (k1 == 9) hi = f2bf(ldf(b1, nn, isf32));
      btab[tid] = lo | (hi << 16);
    }
  }

  __syncthreads();
  int n = tid;
  if (n <= NG){
    if (n == NG) gstart[NG] = NN;
    else {
      int lo = 0, hi = NN;
      while (lo < hi){
        int mid = (lo + hi) >> 1;
        if (batch[mid] < n) lo = mid + 1; else hi = mid;
      }
      gstart[n] = lo;
    }
  }
  if (n >= NN) return;
  int idx[FA];
  #pragma unroll
  for (int f = 0; f < FA; ++f) idx[f] = x[n * FA + f];
  float acc[DA];
  #pragma unroll
  for (int d = 0; d < DA; ++d){
    float a = 0.f;
    #pragma unroll
    for (int f = 0; f < FA; ++f) a += embS[(f * VA + idx[f]) * DA + d];
    acc[d] = a;
  }
  size_t b = (size_t)n * AGS;
  #pragma unroll
  for (int q = 0; q < 4; ++q)
    h0u[b + q] = (u32)f2bf(acc[2*q]) | ((u32)f2bf(acc[2*q+1]) << 16);
  h0u[b + 4] = (u32)f2bf(acc[8]);
}

// ---- scan1 + folded top-level scan (last block does the 293-partial scan) ----
__global__ void k_scan1(const int* __restrict__ deg, int* __restrict__ rowoff,
                        int* __restrict__ part, int* __restrict__ done){
  __shared__ int sh[256];
  __shared__ int amLast;
  int base = blockIdx.x * 1024;
  int t = threadIdx.x;
  int i0 = base + t * 4;
  int v0=0, v1=0, v2=0, v3=0;
  if (i0 + 0 < NN) v0 = deg[i0 + 0];
  if (i0 + 1 < NN) v1 = deg[i0 + 1];
  if (i0 + 2 < NN) v2 = deg[i0 + 2];
  if (i0 + 3 < NN) v3 = deg[i0 + 3];
  int tsum = v0 + v1 + v2 + v3;
  sh[t] = tsum;
  __syncthreads();
  for (int off = 1; off < 256; off <<= 1){
    int add = (t >= off) ? sh[t - off] : 0;
    __syncthreads();
    sh[t] += add;
    __syncthreads();
  }
  int run = sh[t] - tsum;
  if (t == 255) part[blockIdx.x] = sh[255];
  if (i0 + 0 < NN){ rowoff[i0 + 0] = run; run += v0; }
  if (i0 + 1 < NN){ rowoff[i0 + 1] = run; run += v1; }
  if (i0 + 2 < NN){ rowoff[i0 + 2] = run; run += v2; }
  if (i0 + 3 < NN){ rowoff[i0 + 3] = run; run += v3; }

  // fold: last arriving block exclusive-scans the partials
  __threadfence();
  __syncthreads();
  if (t == 0) amLast = (atomicAdd(done, 1) == (int)gridDim.x - 1);
  __syncthreads();
  if (amLast){
    __shared__ int sp[NCHUNK];
    for (int c = t; c < NCHUNK; c += 256) sp[c] = part[c];
    __syncthreads();
    if (t == 0){
      int r = 0;
      for (int c = 0; c < NCHUNK; ++c){ int v = sp[c]; sp[c] = r; r += v; }
    }
    __syncthreads();
    for (int c = t; c < NCHUNK; c += 256) part[c] = sp[c];
  }
}

// rowoff finalize + dinv (deg preserved; no cursor needed anymore)
__global__ void k_scan3(const int* __restrict__ deg, int* __restrict__ rowoff,
                        float* __restrict__ dinv, const int* __restrict__ part){
  int i = blockIdx.x * 256 + threadIdx.x;
  if (i < NN){
    float dv = (float)deg[i];
    rowoff[i] = rowoff[i] + part[i >> 10];
    dinv[i] = rsqrtf(dv + 1.0f);
  }
  if (i == 0) rowoff[NN] = NE;
}

// ---- CSR fill, atomic-free: pos = rowoff[dst] + rank[e] ----
__global__ void k_fill(const int* __restrict__ src, const int* __restrict__ dst,
                       const u16* __restrict__ rank, const int* __restrict__ rowoff,
                       const float* __restrict__ dinv, uint2* __restrict__ csr){
  int e = blockIdx.x * 256 + threadIdx.x;
  if (e < NE){
    int s = src[e], d = dst[e];
    int pos = rowoff[d] + (int)rank[e];
    uint2 ent;
    ent.x = (u32)s;
    ent.y = __float_as_uint(dinv[s] * dinv[d]);
    csr[pos] = ent;
  }
}

// ---- layer-1 CSR gather: agg1 = A' h0; word4 = k8 | bf16(1.0)<<16 (bias slot) ----
__global__ void k_l1csr(const u32* __restrict__ h0u, u32* __restrict__ agg1u,
                        const int* __restrict__ rowoff, const uint2* __restrict__ csr,
                        const float* __restrict__ dinv){
  int n = blockIdx.x * 256 + threadIdx.x;
  if (n >= NN) return;
  float di = dinv[n];
  float c0 = di * di;
  float acc[DA];
  {
    const u32* rp = h0u + (size_t)n * AGS;
    u32 r0 = rp[0], r1 = rp[1], r2 = rp[2], r3 = rp[3], r4 = rp[4];
    acc[0]=c0*bflo(r0); acc[1]=c0*bfhi(r0); acc[2]=c0*bflo(r1); acc[3]=c0*bfhi(r1);
    acc[4]=c0*bflo(r2); acc[5]=c0*bfhi(r2); acc[6]=c0*bflo(r3); acc[7]=c0*bfhi(r3);
    acc[8]=c0*bflo(r4);
  }
  int s0 = rowoff[n], s1 = rowoff[n + 1];
  #pragma unroll 2
  for (int j = s0; j < s1; ++j){
    uint2 ent = csr[j];
    const u32* rp = h0u + (size_t)ent.x * AGS;
    float c = __uint_as_float(ent.y);
    u32 r0 = rp[0], r1 = rp[1], r2 = rp[2], r3 = rp[3], r4 = rp[4];
    acc[0]+=c*bflo(r0); acc[1]+=c*bfhi(r0); acc[2]+=c*bflo(r1); acc[3]+=c*bfhi(r1);
    acc[4]+=c*bflo(r2); acc[5]+=c*bfhi(r2); acc[6]+=c*bflo(r3); acc[7]+=c*bfhi(r3);
    acc[8]+=c*bflo(r4);
  }
  size_t b = (size_t)n * AGS;
  #pragma unroll
  for (int q = 0; q < 4; ++q)
    agg1u[b + q] = (u32)f2bf(acc[2*q]) | ((u32)f2bf(acc[2*q+1]) << 16);
  agg1u[b + 4] = (u32)f2bf(acc[8]) | (0x3F80u << 16);   // k8 | bias-one
}

// ---- fused layer2-aggregate + pool via MFMA (validated round 10) ----
__global__ void k_l2pool(const u32* __restrict__ agg1u, const float* __restrict__ dinv,
                         const int* __restrict__ rowoff, const uint2* __restrict__ csr,
                         const int* __restrict__ gstart, const u32* __restrict__ btab,
                         float* __restrict__ pooled){
  int t = threadIdx.x;
  int g = blockIdx.x * 4 + (t >> 6);
  int lane = t & 63;
  if (g >= NG) return;
  u32 bf[32];
  {
    const u32* bp = btab + lane * 32;
    #pragma unroll
    for (int i = 0; i < 32; ++i) bf[i] = bp[i];
  }
  int a = gstart[g], b = gstart[g + 1];
  int j0 = rowoff[a], j1 = rowoff[b];
  int nself = b - a;
  int M = nself + (j1 - j0);
  float s[8];
  #pragma unroll
  for (int i = 0; i < 8; ++i) s[i] = 0.f;
  int kq = lane >> 4, li = lane & 15;

  #pragma unroll 2
  for (int base = 0; base < M; base += 16){
    u32 a0 = 0, a1 = 0, a2 = 0, a3 = 0;
    float coef = 0.f;
    int i = base + li;
    if (kq < 2 && i < M){
      int n;
      if (i < nself){
        n = a + i;
        float dn = dinv[n];
        coef = dn * dn;
      } else {
        uint2 e = csr[j0 + (i - nself)];
        n = (int)e.x;
        coef = __uint_as_float(e.y);
      }
      const u32* rp = agg1u + (size_t)n * AGS;
      if (kq == 0){ a0 = rp[0]; a1 = rp[1]; a2 = rp[2]; a3 = rp[3]; }
      else        { a0 = rp[4]; }          // [k8, 1.0, 0,0,0,0,0,0]
    }
    float cv0 = __shfl(coef, kq * 4 + 0, 64);
    float cv1 = __shfl(coef, kq * 4 + 1, 64);
    float cv2 = __shfl(coef, kq * 4 + 2, 64);
    float cv3 = __shfl(coef, kq * 4 + 3, 64);
    union { u32 u[4]; bfrag8 v; } au;
    au.u[0] = a0; au.u[1] = a1; au.u[2] = a2; au.u[3] = a3;
    #pragma unroll
    for (int tile = 0; tile < 8; ++tile){
      union { u32 u[4]; bfrag8 v; } bu;
      bu.u[0] = bf[tile*4+0]; bu.u[1] = bf[tile*4+1];
      bu.u[2] = bf[tile*4+2]; bu.u[3] = bf[tile*4+3];
      ffrag4 c = {0.f, 0.f, 0.f, 0.f};
      c = __builtin_amdgcn_mfma_f32_16x16x32_bf16(au.v, bu.v, c, 0, 0, 0);
      s[tile] += fmaxf(c[0], 0.f) * cv0 + fmaxf(c[1], 0.f) * cv1
               + fmaxf(c[2], 0.f) * cv2 + fmaxf(c[3], 0.f) * cv3;
    }
  }
  #pragma unroll
  for (int tile = 0; tile < 8; ++tile){
    float v = s[tile];
    v += __shfl_xor(v, 16, 64);
    v += __shfl_xor(v, 32, 64);
    s[tile] = v;
  }
  if (kq == 0){
    #pragma unroll
    for (int tile = 0; tile < 8; ++tile)
      pooled[(size_t)g * HH + tile * 16 + li] = s[tile];
  }
}

// ---- head: out = (pooled/cnt) @ Wc + (cnt>0 ? bc : 0) + bfc; Wc staged in LDS ----
__global__ void k_head(const float* __restrict__ pooled, const float* __restrict__ wcomb,
                       const float* __restrict__ bcomb, const float* __restrict__ wc,
                       const int* __restrict__ gstart, const int* __restrict__ flag,
                       void* __restrict__ out){
  __shared__ float wS[HH * HH];   // 64 KB
  __shared__ float pl[2][HH];
  int t = threadIdx.x;
  for (int i = t; i < HH * HH; i += 256) wS[i] = wcomb[i];
  __syncthreads();
  int isf32 = flag[0];
  int gg = t >> 7, k = t & 127;
  for (int p = blockIdx.x; p < NG / 2; p += gridDim.x){
    int g = p * 2 + gg;
    int cnt = gstart[g + 1] - gstart[g];
    float inv = 1.0f / (float)(cnt > 1 ? cnt : 1);
    pl[gg][k] = pooled[(size_t)g * HH + k] * inv;
    __syncthreads();
    float acc = wc[OBFC + k] + (cnt > 0 ? bcomb[k] : 0.f);
    #pragma unroll 8
    for (int d = 0; d < HH; ++d) acc += pl[gg][d] * wS[d * HH + k];
    if (isf32) ((float*)out)[(size_t)g * HH + k] = acc;
    else       ((u16*)out)[(size_t)g * HH + k] = f2bf(acc);
    __syncthreads();
  }
}

extern "C" void kernel_launch(void* const* d_in, const int* in_sizes, int n_in,
                              void* d_out, int out_size, void* d_ws, size_t ws_size,
                              hipStream_t stream){
  const int* x     = (const int*)d_in[0];
  const int* ei    = (const int*)d_in[1];
  const int* batch = (const int*)d_in[3];
  const void* aemb = d_in[4];
  const void* W1   = d_in[6];
  const void* b1   = d_in[7];
  const void* W2   = d_in[8];
  const void* b2   = d_in[9];
  const void* Wfc  = d_in[10];
  const void* bfc  = d_in[11];
  const int* srcp = ei;
  const int* dstp = ei + NE;

  // workspace layout — ~28.2 MB (36.3 MB known safe)
  char* p = (char*)d_ws;
  int*   flag   = (int*)p;                 p += 64;
  float* wc     = (float*)p;               p += sizeof(float) * 43944;          // NWC padded
  float* wcomb  = (float*)p;               p += sizeof(float) * (HH * HH);
  float* bcomb  = (float*)p;               p += sizeof(float) * HH;
  u32*   btab   = (u32*)p;                 p += sizeof(u32) * 2048;             // 8 KB B-frag table
  int*   degcur = (int*)p;                 p += sizeof(int) * (NN + 16);        // deg + done counter
  int*   done   = degcur + NN;
  int*   rowoff = (int*)p;                 p += sizeof(int) * (NN + 2);
  int*   part   = (int*)p;                 p += sizeof(int) * 512;
  float* dinv   = (float*)p;               p += sizeof(float) * NN;
  u16*   rank   = (u16*)p;                 p += sizeof(u16) * (NE + 2);         // 1.2 MB
  uint2* csr    = (uint2*)p;               p += sizeof(uint2) * NE;             // 4.8 MB
  int*   gstart = (int*)p;                 p += sizeof(int) * (NG + 4);
  float* pooled = (float*)p;               p += sizeof(float) * (size_t)NG * HH;
  u32*   h0u    = (u32*)p;                 p += sizeof(u32) * (size_t)NN * AGS; // 6 MB
  u32*   agg1u  = (u32*)p;                 p += sizeof(u32) * (size_t)NN * AGS; // 6 MB
  (void)p; (void)ws_size; (void)n_in; (void)in_sizes; (void)out_size;

  hipMemsetAsync(degcur, 0, sizeof(int) * (NN + 16), stream);
  k_pre   <<<(NN + 255) / 256, 256, 0, stream>>>(x, aemb, W1, b1, W2, b2, Wfc, bfc,
                                                 batch, dstp, flag, wc, degcur, rank,
                                                 gstart, h0u, wcomb, bcomb, btab);
  k_scan1 <<<NCHUNK, 256, 0, stream>>>(degcur, rowoff, part, done);
  k_scan3 <<<(NN + 255) / 256, 256, 0, stream>>>(degcur, rowoff, dinv, part);
  k_fill  <<<(NE + 255) / 256, 256, 0, stream>>>(srcp, dstp, rank, rowoff, dinv, csr);
  k_l1csr <<<(NN + 255) / 256, 256, 0, stream>>>(h0u, agg1u, rowoff, csr, dinv);
  k_l2pool<<<NG / 4, 256, 0, stream>>>(agg1u, dinv, rowoff, csr, gstart, btab, pooled);
  k_head  <<<1500, 256, 0, stream>>>(pooled, wcomb, bcomb, wc, gstart, flag, d_out);
}

// Round 13
// 252.737 us; speedup vs baseline: 1.1278x; 1.1278x over previous
//
#include <hip/hip_runtime.h>

#define NN 300000
#define NE 600000
#define NG 12000
#define HH 128
#define FA 9
#define VA 119
#define DA 9
#define AGS 5                          // packed bf16 row stride in u32 (20B rows)
#define NCHUNK ((NN + 1023) / 1024)   // 293

// canonical f32 weight scratch offsets
#define OEMB 0
#define OW1  (FA*VA*DA)            // 9639
#define OB1  (OW1 + DA*HH)         // 10791
#define OW2  (OB1 + HH)            // 10919
#define OB2  (OW2 + HH*HH)         // 27303
#define OWFC (OB2 + HH)            // 27431
#define OBFC (OWFC + HH*HH)        // 43815
#define NWC  (OBFC + HH)           // 43943

typedef unsigned short u16;
typedef unsigned int u32;
typedef __attribute__((ext_vector_type(8))) short bfrag8;   // 8 bf16 (4 VGPRs)
typedef __attribute__((ext_vector_type(4))) float ffrag4;   // 4 f32 acc

__device__ __forceinline__ float bf2f(u16 u){
  union { u32 i; float f; } v; v.i = ((u32)u) << 16; return v.f;
}
__device__ __forceinline__ float bflo(u32 w){
  union { u32 i; float f; } v; v.i = w << 16; return v.f;
}
__device__ __forceinline__ float bfhi(u32 w){
  union { u32 i; float f; } v; v.i = w & 0xFFFF0000u; return v.f;
}
__device__ __forceinline__ u16 f2bf(float f){
  union { float f; u32 i; } v; v.f = f;
  u32 x = v.i;
  return (u16)((x + 0x7FFFu + ((x >> 16) & 1u)) >> 16);
}
__device__ __forceinline__ float ldf(const void* p, int i, int isf32){
  return isf32 ? ((const float*)p)[i] : bf2f(((const u16*)p)[i]);
}
// per-block dtype detect (validated round 3)
__device__ __forceinline__ int detect_isf32(const u16* emb16, int t, int* scnt){
  if (t == 0) *scnt = 0;
  __syncthreads();
  u16 u = emb16[t];
  int e = (u >> 7) & 0xFF;
  if (e >= 96 && e < 126) atomicAdd(scnt, 1);
  __syncthreads();
  return (*scnt >= 200) ? 0 : 1;
}

// ---- k_pre: detect + deg-histogram (captures rank[e]) + canonicalize wc +
//      gstart + embed->h0u + wcomb/bcomb/btab co-work ----
__global__ void k_pre(const int* __restrict__ x, const void* emb, const void* W1,
                      const void* b1, const void* W2, const void* b2,
                      const void* Wfc, const void* bfc,
                      const int* __restrict__ batch, const int* __restrict__ dst,
                      int* __restrict__ flag, float* __restrict__ wc,
                      int* __restrict__ degcur, u16* __restrict__ rank,
                      int* __restrict__ gstart, u32* __restrict__ h0u,
                      float* __restrict__ wcomb, float* __restrict__ bcomb,
                      u32* __restrict__ btab){
  __shared__ float embS[FA * VA * DA];   // 38.6 KB
  __shared__ int scnt;
  int t = threadIdx.x;
  int isf32 = detect_isf32((const u16*)emb, t, &scnt);
  int tid = blockIdx.x * 256 + t;
  int nth = gridDim.x * 256;
  if (tid == 0) flag[0] = isf32;

  // degree histogram: 2 edges/thread; return value = rank within dst
  {
    int e0 = tid * 2;
    if (e0 < NE){
      int r0 = atomicAdd(&degcur[dst[e0]], 1);
      rank[e0] = (u16)r0;
    }
    if (e0 + 1 < NE){
      int r1 = atomicAdd(&degcur[dst[e0 + 1]], 1);
      rank[e0 + 1] = (u16)r1;
    }
  }

  for (int i = t; i < FA * VA * DA; i += 256) embS[i] = ldf(emb, i, isf32);
  for (int i = tid; i < NWC; i += nth){
    float v;
    if      (i < OW1)  v = ldf(emb, i - OEMB, isf32);
    else if (i < OB1)  v = ldf(W1,  i - OW1,  isf32);
    else if (i < OW2)  v = ldf(b1,  i - OB1,  isf32);
    else if (i < OB2)  v = ldf(W2,  i - OW2,  isf32);
    else if (i < OWFC) v = ldf(b2,  i - OB2,  isf32);
    else if (i < OBFC) v = ldf(Wfc, i - OWFC, isf32);
    else               v = ldf(bfc, i - OBFC, isf32);
    wc[i] = v;
  }

  // head-weight co-work: Wc = W2@Wfc, bc = b2@Wfc, MFMA B-frag table
  if (tid < HH * HH){
    int d = tid >> 7, k = tid & 127;
    float s = 0.f;
    #pragma unroll 4
    for (int j = 0; j < HH; ++j) s += ldf(W2, d * HH + j, isf32) * ldf(Wfc, j * HH + k, isf32);
    wcomb[tid] = s;
    if (tid < HH){
      float sb = 0.f;
      #pragma unroll 4
      for (int j = 0; j < HH; ++j) sb += ldf(b2, j, isf32) * ldf(Wfc, j * HH + tid, isf32);
      bcomb[tid] = sb;
    }
    if (tid < 2048){
      // btab[lane*32 + tile*4 + reg]: B[k=(lane>>4)*8 + 2*reg + {0,1}][n=tile*16+(lane&15)]
      int lane = tid >> 5, idx = tid & 31;
      int tile = idx >> 2, reg = idx & 3;
      int kq = lane >> 4, li = lane & 15;
      int nn = tile * 16 + li;
      int k0 = kq * 8 + reg * 2;
      int k1 = k0 + 1;
      u32 lo = 0, hi = 0;
      if (k0 < 9)       lo = f2bf(ldf(W1, k0 * HH + nn, isf32));
      else if (k0 == 9) lo = f2bf(ldf(b1, nn, isf32));
      if (k1 < 9)       hi = f2bf(ldf(W1, k1 * HH + nn, isf32));
      else if (k1 == 9) hi = f2bf(ldf(b1, nn, isf32));
      btab[tid] = lo | (hi << 16);
    }
  }

  __syncthreads();
  int n = tid;
  if (n <= NG){
    if (n == NG) gstart[NG] = NN;
    else {
      int lo = 0, hi = NN;
      while (lo < hi){
        int mid = (lo + hi) >> 1;
        if (batch[mid] < n) lo = mid + 1; else hi = mid;
      }
      gstart[n] = lo;
    }
  }
  if (n >= NN) return;
  int idx[FA];
  #pragma unroll
  for (int f = 0; f < FA; ++f) idx[f] = x[n * FA + f];
  float acc[DA];
  #pragma unroll
  for (int d = 0; d < DA; ++d){
    float a = 0.f;
    #pragma unroll
    for (int f = 0; f < FA; ++f) a += embS[(f * VA + idx[f]) * DA + d];
    acc[d] = a;
  }
  size_t b = (size_t)n * AGS;
  #pragma unroll
  for (int q = 0; q < 4; ++q)
    h0u[b + q] = (u32)f2bf(acc[2*q]) | ((u32)f2bf(acc[2*q+1]) << 16);
  h0u[b + 4] = (u32)f2bf(acc[8]);
}

// ---- exclusive scan of deg -> rowoff (3-kernel; no fences) ----
__global__ void k_scan1(const int* __restrict__ deg, int* __restrict__ rowoff,
                        int* __restrict__ part){
  __shared__ int sh[256];
  int base = blockIdx.x * 1024;
  int t = threadIdx.x;
  int i0 = base + t * 4;
  int v0=0, v1=0, v2=0, v3=0;
  if (i0 + 0 < NN) v0 = deg[i0 + 0];
  if (i0 + 1 < NN) v1 = deg[i0 + 1];
  if (i0 + 2 < NN) v2 = deg[i0 + 2];
  if (i0 + 3 < NN) v3 = deg[i0 + 3];
  int tsum = v0 + v1 + v2 + v3;
  sh[t] = tsum;
  __syncthreads();
  for (int off = 1; off < 256; off <<= 1){
    int add = (t >= off) ? sh[t - off] : 0;
    __syncthreads();
    sh[t] += add;
    __syncthreads();
  }
  int run = sh[t] - tsum;
  if (t == 255) part[blockIdx.x] = sh[255];
  if (i0 + 0 < NN){ rowoff[i0 + 0] = run; run += v0; }
  if (i0 + 1 < NN){ rowoff[i0 + 1] = run; run += v1; }
  if (i0 + 2 < NN){ rowoff[i0 + 2] = run; run += v2; }
  if (i0 + 3 < NN){ rowoff[i0 + 3] = run; run += v3; }
}

__global__ void k_scan2(int* __restrict__ part){
  __shared__ int sh[512];
  int t = threadIdx.x;
  int v = (t < NCHUNK) ? part[t] : 0;
  sh[t] = v;
  __syncthreads();
  for (int off = 1; off < 512; off <<= 1){
    int add = (t >= off) ? sh[t - off] : 0;
    __syncthreads();
    sh[t] += add;
    __syncthreads();
  }
  if (t < NCHUNK) part[t] = sh[t] - v;
}

// rowoff finalize + dinv (deg preserved; no cursor needed)
__global__ void k_scan3(const int* __restrict__ deg, int* __restrict__ rowoff,
                        float* __restrict__ dinv, const int* __restrict__ part){
  int i = blockIdx.x * 256 + threadIdx.x;
  if (i < NN){
    float dv = (float)deg[i];
    rowoff[i] = rowoff[i] + part[i >> 10];
    dinv[i] = rsqrtf(dv + 1.0f);
  }
  if (i == 0) rowoff[NN] = NE;
}

// ---- CSR fill, atomic-free: pos = rowoff[dst] + rank[e] ----
__global__ void k_fill(const int* __restrict__ src, const int* __restrict__ dst,
                       const u16* __restrict__ rank, const int* __restrict__ rowoff,
                       const float* __restrict__ dinv, uint2* __restrict__ csr){
  int e = blockIdx.x * 256 + threadIdx.x;
  if (e < NE){
    int s = src[e], d = dst[e];
    int pos = rowoff[d] + (int)rank[e];
    uint2 ent;
    ent.x = (u32)s;
    ent.y = __float_as_uint(dinv[s] * dinv[d]);
    csr[pos] = ent;
  }
}

// ---- layer-1 CSR gather: agg1 = A' h0; word4 = k8 | bf16(1.0)<<16 (bias slot) ----
__global__ void k_l1csr(const u32* __restrict__ h0u, u32* __restrict__ agg1u,
                        const int* __restrict__ rowoff, const uint2* __restrict__ csr,
                        const float* __restrict__ dinv){
  int n = blockIdx.x * 256 + threadIdx.x;
  if (n >= NN) return;
  float di = dinv[n];
  float c0 = di * di;
  float acc[DA];
  {
    const u32* rp = h0u + (size_t)n * AGS;
    u32 r0 = rp[0], r1 = rp[1], r2 = rp[2], r3 = rp[3], r4 = rp[4];
    acc[0]=c0*bflo(r0); acc[1]=c0*bfhi(r0); acc[2]=c0*bflo(r1); acc[3]=c0*bfhi(r1);
    acc[4]=c0*bflo(r2); acc[5]=c0*bfhi(r2); acc[6]=c0*bflo(r3); acc[7]=c0*bfhi(r3);
    acc[8]=c0*bflo(r4);
  }
  int s0 = rowoff[n], s1 = rowoff[n + 1];
  #pragma unroll 2
  for (int j = s0; j < s1; ++j){
    uint2 ent = csr[j];
    const u32* rp = h0u + (size_t)ent.x * AGS;
    float c = __uint_as_float(ent.y);
    u32 r0 = rp[0], r1 = rp[1], r2 = rp[2], r3 = rp[3], r4 = rp[4];
    acc[0]+=c*bflo(r0); acc[1]+=c*bfhi(r0); acc[2]+=c*bflo(r1); acc[3]+=c*bfhi(r1);
    acc[4]+=c*bflo(r2); acc[5]+=c*bfhi(r2); acc[6]+=c*bflo(r3); acc[7]+=c*bfhi(r3);
    acc[8]+=c*bflo(r4);
  }
  size_t b = (size_t)n * AGS;
  #pragma unroll
  for (int q = 0; q < 4; ++q)
    agg1u[b + q] = (u32)f2bf(acc[2*q]) | ((u32)f2bf(acc[2*q+1]) << 16);
  agg1u[b + 4] = (u32)f2bf(acc[8]) | (0x3F80u << 16);   // k8 | bias-one
}

// ---- fused layer2-aggregate + pool via MFMA (round-10/11 form, no unroll) ----
__global__ void k_l2pool(const u32* __restrict__ agg1u, const float* __restrict__ dinv,
                         const int* __restrict__ rowoff, const uint2* __restrict__ csr,
                         const int* __restrict__ gstart, const u32* __restrict__ btab,
                         float* __restrict__ pooled){
  int t = threadIdx.x;
  int g = blockIdx.x * 4 + (t >> 6);
  int lane = t & 63;
  if (g >= NG) return;
  u32 bf[32];
  {
    const u32* bp = btab + lane * 32;
    #pragma unroll
    for (int i = 0; i < 32; ++i) bf[i] = bp[i];
  }
  int a = gstart[g], b = gstart[g + 1];
  int j0 = rowoff[a], j1 = rowoff[b];
  int nself = b - a;
  int M = nself + (j1 - j0);
  float s[8];
  #pragma unroll
  for (int i = 0; i < 8; ++i) s[i] = 0.f;
  int kq = lane >> 4, li = lane & 15;

  for (int base = 0; base < M; base += 16){
    u32 a0 = 0, a1 = 0, a2 = 0, a3 = 0;
    float coef = 0.f;
    int i = base + li;
    if (kq < 2 && i < M){
      int n;
      if (i < nself){
        n = a + i;
        float dn = dinv[n];
        coef = dn * dn;
      } else {
        uint2 e = csr[j0 + (i - nself)];
        n = (int)e.x;
        coef = __uint_as_float(e.y);
      }
      const u32* rp = agg1u + (size_t)n * AGS;
      if (kq == 0){ a0 = rp[0]; a1 = rp[1]; a2 = rp[2]; a3 = rp[3]; }
      else        { a0 = rp[4]; }          // [k8, 1.0, 0,0,0,0,0,0]
    }
    float cv0 = __shfl(coef, kq * 4 + 0, 64);
    float cv1 = __shfl(coef, kq * 4 + 1, 64);
    float cv2 = __shfl(coef, kq * 4 + 2, 64);
    float cv3 = __shfl(coef, kq * 4 + 3, 64);
    union { u32 u[4]; bfrag8 v; } au;
    au.u[0] = a0; au.u[1] = a1; au.u[2] = a2; au.u[3] = a3;
    #pragma unroll
    for (int tile = 0; tile < 8; ++tile){
      union { u32 u[4]; bfrag8 v; } bu;
      bu.u[0] = bf[tile*4+0]; bu.u[1] = bf[tile*4+1];
      bu.u[2] = bf[tile*4+2]; bu.u[3] = bf[tile*4+3];
      ffrag4 c = {0.f, 0.f, 0.f, 0.f};
      c = __builtin_amdgcn_mfma_f32_16x16x32_bf16(au.v, bu.v, c, 0, 0, 0);
      s[tile] += fmaxf(c[0], 0.f) * cv0 + fmaxf(c[1], 0.f) * cv1
               + fmaxf(c[2], 0.f) * cv2 + fmaxf(c[3], 0.f) * cv3;
    }
  }
  #pragma unroll
  for (int tile = 0; tile < 8; ++tile){
    float v = s[tile];
    v += __shfl_xor(v, 16, 64);
    v += __shfl_xor(v, 32, 64);
    s[tile] = v;
  }
  if (kq == 0){
    #pragma unroll
    for (int tile = 0; tile < 8; ++tile)
      pooled[(size_t)g * HH + tile * 16 + li] = s[tile];
  }
}

// ---- head: out = (pooled/cnt) @ Wc + (cnt>0 ? bc : 0) + bfc; Wc staged in LDS ----
__global__ void k_head(const float* __restrict__ pooled, const float* __restrict__ wcomb,
                       const float* __restrict__ bcomb, const float* __restrict__ wc,
                       const int* __restrict__ gstart, const int* __restrict__ flag,
                       void* __restrict__ out){
  __shared__ float wS[HH * HH];   // 64 KB
  __shared__ float pl[2][HH];
  int t = threadIdx.x;
  for (int i = t; i < HH * HH; i += 256) wS[i] = wcomb[i];
  __syncthreads();
  int isf32 = flag[0];
  int gg = t >> 7, k = t & 127;
  for (int p = blockIdx.x; p < NG / 2; p += gridDim.x){
    int g = p * 2 + gg;
    int cnt = gstart[g + 1] - gstart[g];
    float inv = 1.0f / (float)(cnt > 1 ? cnt : 1);
    pl[gg][k] = pooled[(size_t)g * HH + k] * inv;
    __syncthreads();
    float acc = wc[OBFC + k] + (cnt > 0 ? bcomb[k] : 0.f);
    #pragma unroll 8
    for (int d = 0; d < HH; ++d) acc += pl[gg][d] * wS[d * HH + k];
    if (isf32) ((float*)out)[(size_t)g * HH + k] = acc;
    else       ((u16*)out)[(size_t)g * HH + k] = f2bf(acc);
    __syncthreads();
  }
}

extern "C" void kernel_launch(void* const* d_in, const int* in_sizes, int n_in,
                              void* d_out, int out_size, void* d_ws, size_t ws_size,
                              hipStream_t stream){
  const int* x     = (const int*)d_in[0];
  const int* ei    = (const int*)d_in[1];
  const int* batch = (const int*)d_in[3];
  const void* aemb = d_in[4];
  const void* W1   = d_in[6];
  const void* b1   = d_in[7];
  const void* W2   = d_in[8];
  const void* b2   = d_in[9];
  const void* Wfc  = d_in[10];
  const void* bfc  = d_in[11];
  const int* srcp = ei;
  const int* dstp = ei + NE;

  // workspace layout — ~28.2 MB (36.3 MB known safe)
  char* p = (char*)d_ws;
  int*   flag   = (int*)p;                 p += 64;
  float* wc     = (float*)p;               p += sizeof(float) * 43944;          // NWC padded
  float* wcomb  = (float*)p;               p += sizeof(float) * (HH * HH);
  float* bcomb  = (float*)p;               p += sizeof(float) * HH;
  u32*   btab   = (u32*)p;                 p += sizeof(u32) * 2048;             // 8 KB B-frag table
  int*   degcur = (int*)p;                 p += sizeof(int) * (NN + 16);
  int*   rowoff = (int*)p;                 p += sizeof(int) * (NN + 2);
  int*   part   = (int*)p;                 p += sizeof(int) * 512;
  float* dinv   = (float*)p;               p += sizeof(float) * NN;
  u16*   rank   = (u16*)p;                 p += sizeof(u16) * (NE + 2);         // 1.2 MB
  uint2* csr    = (uint2*)p;               p += sizeof(uint2) * NE;             // 4.8 MB
  int*   gstart = (int*)p;                 p += sizeof(int) * (NG + 4);
  float* pooled = (float*)p;               p += sizeof(float) * (size_t)NG * HH;
  u32*   h0u    = (u32*)p;                 p += sizeof(u32) * (size_t)NN * AGS; // 6 MB
  u32*   agg1u  = (u32*)p;                 p += sizeof(u32) * (size_t)NN * AGS; // 6 MB
  (void)p; (void)ws_size; (void)n_in; (void)in_sizes; (void)out_size;

  hipMemsetAsync(degcur, 0, sizeof(int) * (NN + 16), stream);
  k_pre   <<<(NN + 255) / 256, 256, 0, stream>>>(x, aemb, W1, b1, W2, b2, Wfc, bfc,
                                                 batch, dstp, flag, wc, degcur, rank,
                                                 gstart, h0u, wcomb, bcomb, btab);
  k_scan1 <<<NCHUNK, 256, 0, stream>>>(degcur, rowoff, part);
  k_scan2 <<<1, 512, 0, stream>>>(part);
  k_scan3 <<<(NN + 255) / 256, 256, 0, stream>>>(degcur, rowoff, dinv, part);
  k_fill  <<<(NE + 255) / 256, 256, 0, stream>>>(srcp, dstp, rank, rowoff, dinv, csr);
  k_l1csr <<<(NN + 255) / 256, 256, 0, stream>>>(h0u, agg1u, rowoff, csr, dinv);
  k_l2pool<<<NG / 4, 256, 0, stream>>>(agg1u, dinv, rowoff, csr, gstart, btab, pooled);
  k_head  <<<1500, 256, 0, stream>>>(pooled, wcomb, bcomb, wc, gstart, flag, d_out);
}